// Round 3
// baseline (245.899 us; speedup 1.0000x reference)
//
#include <hip/hip_runtime.h>
#include <stdint.h>
#include <math.h>

// Problem constants (fixed by reference setup_inputs / reference()).
static constexpr int BB = 64;    // batch
static constexpr int TT = 4000;  // time
static constexpr int FF = 128;   // mel bins

// Native clang vector type — required by __builtin_nontemporal_store.
typedef float floatx4 __attribute__((ext_vector_type(4)));

// Per-batch mask parameters, produced by rng_kernel into d_ws.
struct Params {
  uint32_t fm[4];          // 128-bit freq mask
  int ts0, te0, ts1, te1;  // time-mask intervals ([start,end), sentinel 0x7FFFFFFF)
  int vt;                  // valid length
  int pad[3];
};

// ---------------------------------------------------------------------------
// Threefry-2x32, 20 rounds — bit-exact replica of jax._src.prng.threefry2x32.
// ---------------------------------------------------------------------------
__host__ __device__ inline void tf2x32(uint32_t k0, uint32_t k1,
                                       uint32_t c0, uint32_t c1,
                                       uint32_t& o0, uint32_t& o1) {
  uint32_t ks2 = k0 ^ k1 ^ 0x1BD11BDAu;
  uint32_t x0 = c0 + k0;
  uint32_t x1 = c1 + k1;
#define TF_R(r) { x0 += x1; x1 = (x1 << (r)) | (x1 >> (32 - (r))); x1 ^= x0; }
  TF_R(13) TF_R(15) TF_R(26) TF_R(6)
  x0 += k1;  x1 += ks2 + 1u;
  TF_R(17) TF_R(29) TF_R(16) TF_R(24)
  x0 += ks2; x1 += k0 + 2u;
  TF_R(13) TF_R(15) TF_R(26) TF_R(6)
  x0 += k0;  x1 += k1 + 3u;
  TF_R(17) TF_R(29) TF_R(16) TF_R(24)
  x0 += k1;  x1 += ks2 + 4u;
  TF_R(13) TF_R(15) TF_R(26) TF_R(6)
  x0 += ks2; x1 += k0 + 5u;
#undef TF_R
  o0 = x0; o1 = x1;
}

// jax_threefry_partitionable=True random_bits, 32-bit: element j uses counter
// (0, j); output is the xor-fold o0 ^ o1.  [verified bit-exact in R2]
__host__ __device__ inline uint32_t rbits32_part(uint32_t k0, uint32_t k1, uint32_t j) {
  uint32_t o0, o1;
  tf2x32(k0, k1, 0u, j, o0, o1);
  return o0 ^ o1;
}

// jax.random.uniform f32: bitcast((bits >> 9) | 0x3F800000) - 1.0
__device__ inline float u01(uint32_t b) {
  return __uint_as_float((b >> 9) | 0x3F800000u) - 1.0f;
}

struct Keys {
  uint32_t k1f0, k1f1, k2f0, k2f1;  // randint(kf_w)'s internal split keys
  uint32_t kfs0, kfs1;              // kf_s (freq-start uniform)
  uint32_t ktw0, ktw1;              // kt_w (time-width uniform)
  uint32_t kts0, kts1;              // kt_s (time-start uniform)
};

// ---------------------------------------------------------------------------
// Pre-kernel: one lane per batch row computes that row's mask parameters.
// ---------------------------------------------------------------------------
__global__ __launch_bounds__(64)
void rng_kernel(const int* __restrict__ lengths, Params* __restrict__ P, Keys K) {
  const int b = threadIdx.x;  // grid = 1 block x 64 threads
  const int vt = lengths[b];
  uint32_t fm0 = 0, fm1 = 0, fm2 = 0, fm3 = 0;
  int tsv[2], tev[2];
  for (int m = 0; m < 2; ++m) {
    const uint32_t j = (uint32_t)(2 * b + m);  // linear index into (64,2)
    // ---- frequency mask m: randint span=31, multiplier=4 ----
    uint32_t hi = rbits32_part(K.k1f0, K.k1f1, j);
    uint32_t lo = rbits32_part(K.k2f0, K.k2f1, j);
    int w = (int)(((hi % 31u) * 4u + (lo % 31u)) % 31u);
    float fu = u01(rbits32_part(K.kfs0, K.kfs1, j));
    int fs = (int)floorf(fu * (float)(FF - w + 1));
    if (w > 0) {
      for (int f = fs; f < fs + w; ++f) {
        if      (f < 32) fm0 |= 1u << f;
        else if (f < 64) fm1 |= 1u << (f - 32);
        else if (f < 96) fm2 |= 1u << (f - 64);
        else             fm3 |= 1u << (f - 96);
      }
    }
    // ---- time mask m ----
    int twmax = vt < 40 ? vt : 40;
    float tu = u01(rbits32_part(K.ktw0, K.ktw1, j));
    int tw = (int)floorf(tu * (float)(twmax + 1));
    if (tw > twmax) tw = twmax;
    float su = u01(rbits32_part(K.kts0, K.kts1, j));
    int sr = vt - tw + 1; if (sr < 1) sr = 1;
    int ts = (int)floorf(su * (float)sr);
    bool tv = (tw > 0) && (tw < vt) && (vt > 0);
    tsv[m] = tv ? ts : 0x7FFFFFFF;
    tev[m] = tv ? ts + tw : 0x7FFFFFFF;
  }
  Params p;
  p.fm[0] = fm0; p.fm[1] = fm1; p.fm[2] = fm2; p.fm[3] = fm3;
  p.ts0 = tsv[0]; p.te0 = tev[0]; p.ts1 = tsv[1]; p.te1 = tev[1];
  p.vt = vt; p.pad[0] = p.pad[1] = p.pad[2] = 0;
  P[b] = p;
}

// ---------------------------------------------------------------------------
// Main kernel: streaming masked copy with 2x the per-thread MLP of R1.
// Block = 128 threads covers one 32-row x 128-f tile (16 KB).  Each thread:
// lane = f granule (0..31), r = tid>>5 (0..3); owns rows t0 + r + 4k for
// k = 0..7 — EIGHT independent 16 B loads issued up-front (128 B in
// flight/thread, 8 KB/wave), then 8 masked nontemporal stores.
// grid = (125, 64) = 8000 blocks, 2 waves each; no LDS, no __syncthreads.
// ---------------------------------------------------------------------------
__global__ __launch_bounds__(128)
void BatchSpecAugment_kernel(const floatx4* __restrict__ mv,
                             const Params* __restrict__ P,
                             floatx4* __restrict__ ov) {
  const int b = blockIdx.y;
  const Params p = P[b];  // uniform address -> scalar loads

  const int lane = threadIdx.x & 31;   // f position (16B granules)
  const int r    = threadIdx.x >> 5;   // 0..3
  const int c    = lane * 4;
  const uint32_t nibF = (p.fm[c >> 5] >> (c & 31)) & 0xFu;
  const int ts0 = p.ts0, te0 = p.te0, ts1 = p.ts1, te1 = p.te1;
  const int vt  = p.vt;

  const int t0 = blockIdx.x * 32;                      // tile base row
  // thread's first row: t0 + r; subsequent rows stride by 4 (k = 0..7)
  const size_t base = ((size_t)b * TT + t0 + r) * (FF / 4) + lane;

  floatx4 v[8];
#pragma unroll
  for (int k = 0; k < 8; ++k) v[k] = mv[base + (size_t)k * 4 * (FF / 4)];

#pragma unroll
  for (int k = 0; k < 8; ++k) {
    const int t = t0 + r + 4 * k;
    const bool tm = (t >= ts0 && t < te0) || (t >= ts1 && t < te1);
    const uint32_t nib = tm ? 0xFu : (t < vt ? nibF : 0u);
    floatx4 o;
    o.x = (nib & 1u) ? 0.0f : v[k].x;
    o.y = (nib & 2u) ? 0.0f : v[k].y;
    o.z = (nib & 4u) ? 0.0f : v[k].z;
    o.w = (nib & 8u) ? 0.0f : v[k].w;
    __builtin_nontemporal_store(o, &ov[base + (size_t)k * 4 * (FF / 4)]);
  }
}

extern "C" void kernel_launch(void* const* d_in, const int* in_sizes, int n_in,
                              void* d_out, int out_size, void* d_ws, size_t ws_size,
                              hipStream_t stream) {
  (void)in_sizes; (void)n_in; (void)out_size; (void)ws_size;

  // Host-side key derivation (partitionable threefry; verified R2).
  uint32_t kfw0, kfw1, kfs0, kfs1, ktw0, ktw1, kts0, kts1;
  tf2x32(0u, 42u, 0u, 0u, kfw0, kfw1);  // kf_w
  tf2x32(0u, 42u, 0u, 1u, kfs0, kfs1);  // kf_s
  tf2x32(0u, 42u, 0u, 2u, ktw0, ktw1);  // kt_w
  tf2x32(0u, 42u, 0u, 3u, kts0, kts1);  // kt_s

  uint32_t k1f0, k1f1, k2f0, k2f1;
  tf2x32(kfw0, kfw1, 0u, 0u, k1f0, k1f1);  // randint higher_bits key
  tf2x32(kfw0, kfw1, 0u, 1u, k2f0, k2f1);  // randint lower_bits key

  Keys K;
  K.k1f0 = k1f0; K.k1f1 = k1f1;
  K.k2f0 = k2f0; K.k2f1 = k2f1;
  K.kfs0 = kfs0; K.kfs1 = kfs1;
  K.ktw0 = ktw0; K.ktw1 = ktw1;
  K.kts0 = kts0; K.kts1 = kts1;

  const floatx4* mel     = (const floatx4*)d_in[0];
  const int*     lengths = (const int*)d_in[1];
  floatx4*       outp    = (floatx4*)d_out;
  Params*        params  = (Params*)d_ws;

  rng_kernel<<<dim3(1), dim3(64), 0, stream>>>(lengths, params, K);

  dim3 grid(TT / 32, BB), block(128);
  BatchSpecAugment_kernel<<<grid, block, 0, stream>>>(mel, params, outp);
}

// Round 6
// 232.168 us; speedup vs baseline: 1.0591x; 1.0591x over previous
//
#include <hip/hip_runtime.h>
#include <stdint.h>
#include <math.h>

// Problem constants (fixed by reference setup_inputs / reference()).
static constexpr int BB = 64;    // batch
static constexpr int TT = 4000;  // time
static constexpr int FF = 128;   // mel bins

// Native clang vector type — required by __builtin_nontemporal_store.
typedef float floatx4 __attribute__((ext_vector_type(4)));

// Per-batch mask parameters, produced by rng_kernel into d_ws.
// Layout as 12 u32 words: fm[4], ts0, te0, ts1, te1, vt, pad[3].
struct Params {
  uint32_t fm[4];
  int ts0, te0, ts1, te1;
  int vt;
  int pad[3];
};

// ---------------------------------------------------------------------------
// Threefry-2x32, 20 rounds — bit-exact replica of jax._src.prng.threefry2x32.
// ---------------------------------------------------------------------------
__host__ __device__ inline void tf2x32(uint32_t k0, uint32_t k1,
                                       uint32_t c0, uint32_t c1,
                                       uint32_t& o0, uint32_t& o1) {
  uint32_t ks2 = k0 ^ k1 ^ 0x1BD11BDAu;
  uint32_t x0 = c0 + k0;
  uint32_t x1 = c1 + k1;
#define TF_R(r) { x0 += x1; x1 = (x1 << (r)) | (x1 >> (32 - (r))); x1 ^= x0; }
  TF_R(13) TF_R(15) TF_R(26) TF_R(6)
  x0 += k1;  x1 += ks2 + 1u;
  TF_R(17) TF_R(29) TF_R(16) TF_R(24)
  x0 += ks2; x1 += k0 + 2u;
  TF_R(13) TF_R(15) TF_R(26) TF_R(6)
  x0 += k0;  x1 += k1 + 3u;
  TF_R(17) TF_R(29) TF_R(16) TF_R(24)
  x0 += k1;  x1 += ks2 + 4u;
  TF_R(13) TF_R(15) TF_R(26) TF_R(6)
  x0 += ks2; x1 += k0 + 5u;
#undef TF_R
  o0 = x0; o1 = x1;
}

// jax_threefry_partitionable=True random_bits, 32-bit: element j uses counter
// (0, j); output is the xor-fold o0 ^ o1.  [verified bit-exact in R2]
__host__ __device__ inline uint32_t rbits32_part(uint32_t k0, uint32_t k1, uint32_t j) {
  uint32_t o0, o1;
  tf2x32(k0, k1, 0u, j, o0, o1);
  return o0 ^ o1;
}

// jax.random.uniform f32: bitcast((bits >> 9) | 0x3F800000) - 1.0
__device__ inline float u01(uint32_t b) {
  return __uint_as_float((b >> 9) | 0x3F800000u) - 1.0f;
}

struct Keys {
  uint32_t k1f0, k1f1, k2f0, k2f1;  // randint(kf_w)'s internal split keys
  uint32_t kfs0, kfs1;              // kf_s (freq-start uniform)
  uint32_t ktw0, ktw1;              // kt_w (time-width uniform)
  uint32_t kts0, kts1;              // kt_s (time-start uniform)
};

// ---------------------------------------------------------------------------
// Pre-kernel: one lane per batch row computes that row's mask parameters.
// ---------------------------------------------------------------------------
__global__ __launch_bounds__(64)
void rng_kernel(const int* __restrict__ lengths, Params* __restrict__ P, Keys K) {
  const int b = threadIdx.x;  // grid = 1 block x 64 threads
  const int vt = lengths[b];
  uint32_t fm0 = 0, fm1 = 0, fm2 = 0, fm3 = 0;
  int tsv[2], tev[2];
  for (int m = 0; m < 2; ++m) {
    const uint32_t j = (uint32_t)(2 * b + m);  // linear index into (64,2)
    // ---- frequency mask m: randint span=31, multiplier=4 ----
    uint32_t hi = rbits32_part(K.k1f0, K.k1f1, j);
    uint32_t lo = rbits32_part(K.k2f0, K.k2f1, j);
    int w = (int)(((hi % 31u) * 4u + (lo % 31u)) % 31u);
    float fu = u01(rbits32_part(K.kfs0, K.kfs1, j));
    int fs = (int)floorf(fu * (float)(FF - w + 1));
    if (w > 0) {
      for (int f = fs; f < fs + w; ++f) {
        if      (f < 32) fm0 |= 1u << f;
        else if (f < 64) fm1 |= 1u << (f - 32);
        else if (f < 96) fm2 |= 1u << (f - 64);
        else             fm3 |= 1u << (f - 96);
      }
    }
    // ---- time mask m ----
    int twmax = vt < 40 ? vt : 40;
    float tu = u01(rbits32_part(K.ktw0, K.ktw1, j));
    int tw = (int)floorf(tu * (float)(twmax + 1));
    if (tw > twmax) tw = twmax;
    float su = u01(rbits32_part(K.kts0, K.kts1, j));
    int sr = vt - tw + 1; if (sr < 1) sr = 1;
    int ts = (int)floorf(su * (float)sr);
    bool tv = (tw > 0) && (tw < vt) && (vt > 0);
    tsv[m] = tv ? ts : 0x7FFFFFFF;
    tev[m] = tv ? ts + tw : 0x7FFFFFFF;
  }
  Params p;
  p.fm[0] = fm0; p.fm[1] = fm1; p.fm[2] = fm2; p.fm[3] = fm3;
  p.ts0 = tsv[0]; p.te0 = tev[0]; p.ts1 = tsv[1]; p.te1 = tev[1];
  p.vt = vt; p.pad[0] = p.pad[1] = p.pad[2] = 0;
  P[b] = p;
}

// ---------------------------------------------------------------------------
// Main kernel: streaming masked copy with FORCED 8-deep per-thread MLP.
//
// R0-R3 lesson (rocprof VGPR_Count = 16/28 despite v[4]/v[8] source arrays):
// the compiler fuses the load loop into the store loop, producing serial
// load->waitcnt->store chains (~1 load in flight/thread) — that was the
// ~3.4 TB/s cap.  Fix: issue all 8 loads as named scalars, then a compiler
// memory fence (asm volatile "" with memory clobber) so no store hoists
// above the loads and no load sinks below it.  (R4/R5 used
// __builtin_amdgcn_sched_barrier(0); swapped for the vanilla fence after
// two unexplained container failures — same semantics for this purpose.)
// No local arrays anywhere (R2/R3's alloca got promoted to LDS:
// LDS_Block_Size 48 B/thread + 1.25M bank-conflict cycles).
//
// Block = 128 threads, one 32-row x 128-f tile; lane = f granule (0..31),
// r = tid>>5 (0..3); rows t0 + r + 4k, k = 0..7.  grid = (125, 64).
// ---------------------------------------------------------------------------
__global__ __launch_bounds__(128)
void BatchSpecAugment_kernel(const floatx4* __restrict__ mv,
                             const uint32_t* __restrict__ Pw,
                             floatx4* __restrict__ ov) {
  const int b = blockIdx.y;
  const int lane = threadIdx.x & 31;   // f position (16B granules)
  const int r    = threadIdx.x >> 5;   // 0..3
  const int c    = lane * 4;

  // Direct scalar loads; base index uniform per block, fm word per-lane.
  const uint32_t fmw = Pw[b * 12 + (c >> 5)];
  const uint32_t nibF = (fmw >> (c & 31)) & 0xFu;
  const int ts0 = (int)Pw[b * 12 + 4];
  const int te0 = (int)Pw[b * 12 + 5];
  const int ts1 = (int)Pw[b * 12 + 6];
  const int te1 = (int)Pw[b * 12 + 7];
  const int vt  = (int)Pw[b * 12 + 8];

  const int t0 = blockIdx.x * 32;                      // tile base row
  const size_t base = ((size_t)b * TT + t0 + r) * (FF / 4) + lane;

  floatx4 v0 = mv[base + 0 * 4 * (FF / 4)];
  floatx4 v1 = mv[base + 1 * 4 * (FF / 4)];
  floatx4 v2 = mv[base + 2 * 4 * (FF / 4)];
  floatx4 v3 = mv[base + 3 * 4 * (FF / 4)];
  floatx4 v4 = mv[base + 4 * 4 * (FF / 4)];
  floatx4 v5 = mv[base + 5 * 4 * (FF / 4)];
  floatx4 v6 = mv[base + 6 * 4 * (FF / 4)];
  floatx4 v7 = mv[base + 7 * 4 * (FF / 4)];

  // Compiler fence: loads above cannot sink below, stores below cannot
  // hoist above — forces all 8 loads to issue before any store waits.
  asm volatile("" ::: "memory");

#define MASK_STORE(K_, VK_)                                                  \
  {                                                                          \
    const int t = t0 + r + 4 * (K_);                                         \
    const bool tm = (t >= ts0 && t < te0) || (t >= ts1 && t < te1);          \
    const uint32_t nib = tm ? 0xFu : (t < vt ? nibF : 0u);                   \
    floatx4 o;                                                               \
    o.x = (nib & 1u) ? 0.0f : (VK_).x;                                       \
    o.y = (nib & 2u) ? 0.0f : (VK_).y;                                       \
    o.z = (nib & 4u) ? 0.0f : (VK_).z;                                       \
    o.w = (nib & 8u) ? 0.0f : (VK_).w;                                       \
    __builtin_nontemporal_store(o, &ov[base + (size_t)(K_) * 4 * (FF / 4)]); \
  }

  MASK_STORE(0, v0)
  MASK_STORE(1, v1)
  MASK_STORE(2, v2)
  MASK_STORE(3, v3)
  MASK_STORE(4, v4)
  MASK_STORE(5, v5)
  MASK_STORE(6, v6)
  MASK_STORE(7, v7)
#undef MASK_STORE
}

extern "C" void kernel_launch(void* const* d_in, const int* in_sizes, int n_in,
                              void* d_out, int out_size, void* d_ws, size_t ws_size,
                              hipStream_t stream) {
  (void)in_sizes; (void)n_in; (void)out_size; (void)ws_size;

  // Host-side key derivation (partitionable threefry; verified R2).
  uint32_t kfw0, kfw1, kfs0, kfs1, ktw0, ktw1, kts0, kts1;
  tf2x32(0u, 42u, 0u, 0u, kfw0, kfw1);  // kf_w
  tf2x32(0u, 42u, 0u, 1u, kfs0, kfs1);  // kf_s
  tf2x32(0u, 42u, 0u, 2u, ktw0, ktw1);  // kt_w
  tf2x32(0u, 42u, 0u, 3u, kts0, kts1);  // kt_s

  uint32_t k1f0, k1f1, k2f0, k2f1;
  tf2x32(kfw0, kfw1, 0u, 0u, k1f0, k1f1);  // randint higher_bits key
  tf2x32(kfw0, kfw1, 0u, 1u, k2f0, k2f1);  // randint lower_bits key

  Keys K;
  K.k1f0 = k1f0; K.k1f1 = k1f1;
  K.k2f0 = k2f0; K.k2f1 = k2f1;
  K.kfs0 = kfs0; K.kfs1 = kfs1;
  K.ktw0 = ktw0; K.ktw1 = ktw1;
  K.kts0 = kts0; K.kts1 = kts1;

  const floatx4* mel     = (const floatx4*)d_in[0];
  const int*     lengths = (const int*)d_in[1];
  floatx4*       outp    = (floatx4*)d_out;
  Params*        params  = (Params*)d_ws;

  rng_kernel<<<dim3(1), dim3(64), 0, stream>>>(lengths, params, K);

  dim3 grid(TT / 32, BB), block(128);
  BatchSpecAugment_kernel<<<grid, block, 0, stream>>>(mel, (const uint32_t*)params, outp);
}